// Round 3
// baseline (340.523 us; speedup 1.0000x reference)
//
#include <hip/hip_runtime.h>

#define HDIM 128
#define NBH  512      // blocks per half in the gemm

typedef __bf16 bf16_t;
typedef bf16_t bf16x8 __attribute__((ext_vector_type(8)));
typedef float  f32x4  __attribute__((ext_vector_type(4)));

__device__ __forceinline__ unsigned short f2bf_rne(float f) {
    unsigned int u = __float_as_uint(f);
    u += 0x7fffu + ((u >> 16) & 1u);   // round-to-nearest-even
    return (unsigned short)(u >> 16);
}
__device__ __forceinline__ unsigned int pk_bf2(float a, float b) {
    return (unsigned int)f2bf_rne(a) | ((unsigned int)f2bf_rne(b) << 16);
}

// W1 [2*128 k][128 n] fp32 -> Wt [2][n=128][k=128] bf16 (n-major, k-contiguous)
__global__ __launch_bounds__(256) void convert_w1(
    const float* __restrict__ W1, unsigned short* __restrict__ Wt)
{
    const int o = blockIdx.x * 256 + threadIdx.x;     // 0..32767
    const int g = o >> 14, rem = o & 16383, n = rem >> 7, k = rem & 127;
    Wt[o] = f2bf_rne(W1[g * 16384 + k * 128 + n]);
}

// C_bf16[M,128] = bf16(Z[M,128]) @ bf16(W[128,128]) (+ b1 if second half).
// v5: no LDS, no persistent 128-VGPR W file (v4's spill risk). W fragments
// are (re)loaded per-MFMA from global memory — W is 32 KB and L2-hot in
// every XCD, so these are ~200-cycle L2 hits fully overlapped by MFMA.
// The asm() pointer-launder stops LICM from hoisting all 32 W loads back
// into registers (which would recreate v4's register pressure).
__global__ __launch_bounds__(256) void node_gemm_v5(
    const float* __restrict__ Zs, const float* __restrict__ Zd,
    const unsigned short* __restrict__ Wt, const float* __restrict__ b1,
    unsigned short* __restrict__ Abuf, unsigned short* __restrict__ Bbuf,
    int M)
{
    const bool second = (blockIdx.x >= NBH);
    const float* __restrict__ Z    = second ? Zd : Zs;
    const unsigned short* Wbase    = Wt + (second ? 128 * 128 : 0);
    unsigned short* __restrict__ C = second ? Bbuf : Abuf;
    const int bx = second ? (blockIdx.x - NBH) : blockIdx.x;
    const int t  = threadIdx.x;

    const int lane = t & 63;
    const int wave = t >> 6;
    const int m    = lane & 15;     // Z row within wave's 16 / D col group
    const int quad = lane >> 4;

    const int ntiles = (M + 63) >> 6;
    for (int tile = bx; tile < ntiles; tile += NBH) {
        const int row0 = tile * 64;
        const int r    = row0 + wave * 16 + m;
        const int rc   = (r < M) ? r : (M - 1);
        const float* zrow = Z + (size_t)rc * HDIM;

        // launder W pointer: opaque per tile-iteration -> loads stay in-loop
        const unsigned short* W = Wbase;
        asm volatile("" : "+v"(W));

        f32x4 acc[8] = {};
        #pragma unroll
        for (int ks = 0; ks < 4; ++ks) {
            // B-op fragment: Z[rc][ks*32 + quad*8 .. +8] fp32 -> bf16x8
            const float4 v0 = *reinterpret_cast<const float4*>(zrow + ks * 32 + quad * 8);
            const float4 v1 = *reinterpret_cast<const float4*>(zrow + ks * 32 + quad * 8 + 4);
            union { unsigned int u[4]; bf16x8 h; } zf;
            zf.u[0] = pk_bf2(v0.x, v0.y);
            zf.u[1] = pk_bf2(v0.z, v0.w);
            zf.u[2] = pk_bf2(v1.x, v1.y);
            zf.u[3] = pk_bf2(v1.z, v1.w);
            #pragma unroll
            for (int ct = 0; ct < 8; ++ct) {
                const bf16x8 wf = *reinterpret_cast<const bf16x8*>(
                    W + (ct * 16 + m) * HDIM + ks * 32 + quad * 8);
                acc[ct] = __builtin_amdgcn_mfma_f32_16x16x32_bf16(
                    wf, zf.h, acc[ct], 0, 0, 0);
            }
        }

        // ---- epilogue: +bias, fp32->bf16, 8-B stores ----
        if (r < M) {
            unsigned short* crow = C + (size_t)r * HDIM;
            #pragma unroll
            for (int ct = 0; ct < 8; ++ct) {
                const int col = ct * 16 + quad * 4;
                float4 bv = make_float4(0.f, 0.f, 0.f, 0.f);
                if (second) bv = *reinterpret_cast<const float4*>(b1 + col);
                uint2 o;
                o.x = pk_bf2(acc[ct][0] + bv.x, acc[ct][1] + bv.y);
                o.y = pk_bf2(acc[ct][2] + bv.z, acc[ct][3] + bv.w);
                *reinterpret_cast<uint2*>(crow + col) = o;
            }
        }
    }
}

// out[e] = relu(A[rows[e]] + B[cols[e]]) . W2 + b2, A/B bf16 (b1 folded in B).
// v1 body (best measured), parameterized by separate row/col pointers so the
// launcher can split the edge range into two dispatches (observability: keeps
// every decode dispatch below the gemm's unknown duration).
__global__ __launch_bounds__(256) void edge_decode_bf16(
    const unsigned short* __restrict__ A, const unsigned short* __restrict__ Bm,
    const int* __restrict__ rows, const int* __restrict__ cols,
    const float* __restrict__ W2, const float* __restrict__ b2,
    float* __restrict__ out, int n)
{
    const int t   = threadIdx.x;
    const int sub = t & 15;
    const int grp = t >> 4;

    float w2r[8];
    #pragma unroll
    for (int i = 0; i < 8; ++i) w2r[i] = W2[sub * 8 + i];
    const float b2s = b2[0];

    const int stride = gridDim.x * 16;
    for (int e = blockIdx.x * 16 + grp; e < n; e += stride) {
        const int r = rows[e];
        const int c = cols[e];
        const uint4 av = *reinterpret_cast<const uint4*>(A  + (size_t)r * HDIM + sub * 8);
        const uint4 bv = *reinterpret_cast<const uint4*>(Bm + (size_t)c * HDIM + sub * 8);

        float s = 0.f;
        #pragma unroll
        for (int i = 0; i < 4; ++i) {
            const unsigned int ua = (&av.x)[i];
            const unsigned int ub = (&bv.x)[i];
            s += fmaxf(__uint_as_float(ua << 16)         + __uint_as_float(ub << 16),         0.f) * w2r[2 * i];
            s += fmaxf(__uint_as_float(ua & 0xffff0000u) + __uint_as_float(ub & 0xffff0000u), 0.f) * w2r[2 * i + 1];
        }
        s += __shfl_xor(s, 1);
        s += __shfl_xor(s, 2);
        s += __shfl_xor(s, 4);
        s += __shfl_xor(s, 8);
        if (sub == 0) out[e] = s + b2s;
    }
}

extern "C" void kernel_launch(void* const* d_in, const int* in_sizes, int n_in,
                              void* d_out, int out_size, void* d_ws, size_t ws_size,
                              hipStream_t stream)
{
    const float* z_src = (const float*)d_in[0];
    const float* z_dst = (const float*)d_in[1];
    const int*   eidx  = (const int*)d_in[2];
    const float* W1    = (const float*)d_in[3];
    const float* b1    = (const float*)d_in[4];
    const float* W2    = (const float*)d_in[5];
    const float* b2    = (const float*)d_in[6];
    float*       outp  = (float*)d_out;

    const int Nn = in_sizes[0] / HDIM;    // 100000
    const int E  = in_sizes[2] / 2;       // 2000000

    unsigned short* Abuf = (unsigned short*)d_ws;
    unsigned short* Bbuf = Abuf + (size_t)Nn * HDIM;
    unsigned short* Wt   = Bbuf + (size_t)Nn * HDIM;

    convert_w1<<<128, 256, 0, stream>>>(W1, Wt);

    node_gemm_v5<<<2 * NBH, 256, 0, stream>>>(z_src, z_dst, Wt, b1, Abuf, Bbuf, Nn);

    // decode split into two half-range dispatches (~69 us each):
    // anything slower than a half must surface in the top-5 counters.
    const int Eh = E / 2;
    edge_decode_bf16<<<8192, 256, 0, stream>>>(
        Abuf, Bbuf, eidx, eidx + E, W2, b2, outp, Eh);
    edge_decode_bf16<<<8192, 256, 0, stream>>>(
        Abuf, Bbuf, eidx + Eh, eidx + E + Eh, W2, b2, outp + Eh, E - Eh);
}

// Round 4
// 291.405 us; speedup vs baseline: 1.1686x; 1.1686x over previous
//
#include <hip/hip_runtime.h>

#define HDIM 128

typedef __bf16 bf16_t;
typedef bf16_t bf16x8 __attribute__((ext_vector_type(8)));
typedef float  f32x4  __attribute__((ext_vector_type(4)));

__device__ __forceinline__ unsigned short f2bf_rne(float f) {
    unsigned int u = __float_as_uint(f);
    u += 0x7fffu + ((u >> 16) & 1u);   // round-to-nearest-even
    return (unsigned short)(u >> 16);
}
__device__ __forceinline__ unsigned int pk_bf2(float a, float b) {
    return (unsigned int)f2bf_rne(a) | ((unsigned int)f2bf_rne(b) << 16);
}

// W1 [2*128 k][128 n] fp32 -> Wt [2][n=128][k=128] bf16 (n-major, k-contiguous)
__global__ __launch_bounds__(256) void convert_w1(
    const float* __restrict__ W1, unsigned short* __restrict__ Wt)
{
    const int o = blockIdx.x * 256 + threadIdx.x;     // 0..32767
    const int g = o >> 14, rem = o & 16383, n = rem >> 7, k = rem & 127;
    Wt[o] = f2bf_rne(W1[g * 16384 + k * 128 + n]);
}

// C_bf16[M,128] = bf16(Z[M,128]) @ bf16(W[128,128]) (+ b1 if second half).
// v6: latency-bind fix for v5 (98 us, all pipes <15% busy):
//  - one 64-row tile per block, grid = 2*tiles (3126): 12 blocks/CU queued,
//    ~5 resident (32 KB LDS) vs v5's 4 -> real wave-level overlap.
//  - W staged to LDS ONCE per block, 16B-chunk XOR swizzle (chunk ^= row&7,
//    T2): v3's pitch-136 layout was ~8-way bank-aliased on ds_read_b128.
//  - Z global loads issued BEFORE staging+barrier: ~900cy HBM latency hides
//    under W stage instead of serializing ahead of the MFMA chain.
__global__ __launch_bounds__(256) void node_gemm_v6(
    const float* __restrict__ Zs, const float* __restrict__ Zd,
    const unsigned short* __restrict__ Wt, const float* __restrict__ b1,
    unsigned short* __restrict__ Abuf, unsigned short* __restrict__ Bbuf,
    int M, int tiles_per_half)
{
    __shared__ unsigned short wlds[128 * 128];   // 32 KB

    const bool second = (blockIdx.x >= tiles_per_half);
    const int tile = second ? (blockIdx.x - tiles_per_half) : blockIdx.x;
    const float* __restrict__ Z          = second ? Zd : Zs;
    const unsigned short* __restrict__ W = Wt + (second ? 128 * 128 : 0);
    unsigned short* __restrict__ C       = second ? Bbuf : Abuf;
    const int t    = threadIdx.x;
    const int lane = t & 63;
    const int wave = t >> 6;
    const int m    = lane & 15;     // Z row within wave's 16 / D col group
    const int quad = lane >> 4;

    // ---- issue Z loads first (HBM latency hides under W staging) ----
    const int r  = tile * 64 + wave * 16 + m;
    const int rc = (r < M) ? r : (M - 1);
    const float* zrow = Z + (size_t)rc * HDIM;
    float4 zv[4][2];
    #pragma unroll
    for (int ks = 0; ks < 4; ++ks) {
        zv[ks][0] = *reinterpret_cast<const float4*>(zrow + ks * 32 + quad * 8);
        zv[ks][1] = *reinterpret_cast<const float4*>(zrow + ks * 32 + quad * 8 + 4);
    }

    // ---- stage W (128 rows x 16 chunks of 16B), XOR-swizzled chunks ----
    // chunk cc of row n stored at chunk (cc ^ (n&7)): spreads the 16-row
    // column-slice read (ds_read_b128, all lanes same cc) across banks.
    #pragma unroll
    for (int j = 0; j < 8; ++j) {
        const int u = t + 256 * j;          // 0..2047
        const int n = u >> 4, cc = u & 15;
        const uint4 v = *reinterpret_cast<const uint4*>(W + n * 128 + cc * 8);
        *reinterpret_cast<uint4*>(wlds + n * 128 + (cc ^ (n & 7)) * 8) = v;
    }
    __syncthreads();

    // ---- pack Z to bf16 fragments ----
    union { unsigned int u[4]; bf16x8 h; } zf[4];
    #pragma unroll
    for (int ks = 0; ks < 4; ++ks) {
        zf[ks].u[0] = pk_bf2(zv[ks][0].x, zv[ks][0].y);
        zf[ks].u[1] = pk_bf2(zv[ks][0].z, zv[ks][0].w);
        zf[ks].u[2] = pk_bf2(zv[ks][1].x, zv[ks][1].y);
        zf[ks].u[3] = pk_bf2(zv[ks][1].z, zv[ks][1].w);
    }

    // ---- MFMA: acc[ct] += W[ct*16+m, ks*32..] * z ----
    f32x4 acc[8] = {};
    #pragma unroll
    for (int ks = 0; ks < 4; ++ks) {
        const int cidx = (ks * 4 + quad) ^ (m & 7);   // swizzled 16B-chunk
        #pragma unroll
        for (int ct = 0; ct < 8; ++ct) {
            const bf16x8 wf = *reinterpret_cast<const bf16x8*>(
                wlds + (ct * 16 + m) * 128 + cidx * 8);
            acc[ct] = __builtin_amdgcn_mfma_f32_16x16x32_bf16(
                wf, zf[ks].h, acc[ct], 0, 0, 0);
        }
    }

    // ---- epilogue: +bias, fp32->bf16, 8-B stores ----
    if (r < M) {
        unsigned short* crow = C + (size_t)r * HDIM;
        #pragma unroll
        for (int ct = 0; ct < 8; ++ct) {
            const int col = ct * 16 + quad * 4;
            float4 bv = make_float4(0.f, 0.f, 0.f, 0.f);
            if (second) bv = *reinterpret_cast<const float4*>(b1 + col);
            uint2 o;
            o.x = pk_bf2(acc[ct][0] + bv.x, acc[ct][1] + bv.y);
            o.y = pk_bf2(acc[ct][2] + bv.z, acc[ct][3] + bv.w);
            *reinterpret_cast<uint2*>(crow + col) = o;
        }
    }
}

// out[e] = relu(A[row[e]] + B[col[e]]) . W2 + b2, A/B bf16 (b1 folded into B).
// 16 lanes per edge; lane handles 8 features (16 B load/operand).
// (R0 body, single dispatch — the two-way split regressed ~40 us.)
__global__ __launch_bounds__(256) void edge_decode_bf16(
    const unsigned short* __restrict__ A, const unsigned short* __restrict__ Bm,
    const int* __restrict__ idx,   // [2*E]: rows then cols
    const float* __restrict__ W2, const float* __restrict__ b2,
    float* __restrict__ out, int E)
{
    const int t   = threadIdx.x;
    const int sub = t & 15;
    const int grp = t >> 4;

    float w2r[8];
    #pragma unroll
    for (int i = 0; i < 8; ++i) w2r[i] = W2[sub * 8 + i];
    const float b2s = b2[0];

    const int stride = gridDim.x * 16;
    for (int e = blockIdx.x * 16 + grp; e < E; e += stride) {
        const int r = idx[e];
        const int c = idx[E + e];
        const uint4 av = *reinterpret_cast<const uint4*>(A  + (size_t)r * HDIM + sub * 8);
        const uint4 bv = *reinterpret_cast<const uint4*>(Bm + (size_t)c * HDIM + sub * 8);

        float s = 0.f;
        #pragma unroll
        for (int i = 0; i < 4; ++i) {
            const unsigned int ua = (&av.x)[i];
            const unsigned int ub = (&bv.x)[i];
            s += fmaxf(__uint_as_float(ua << 16)         + __uint_as_float(ub << 16),         0.f) * w2r[2 * i];
            s += fmaxf(__uint_as_float(ua & 0xffff0000u) + __uint_as_float(ub & 0xffff0000u), 0.f) * w2r[2 * i + 1];
        }
        s += __shfl_xor(s, 1);
        s += __shfl_xor(s, 2);
        s += __shfl_xor(s, 4);
        s += __shfl_xor(s, 8);
        if (sub == 0) out[e] = s + b2s;
    }
}

extern "C" void kernel_launch(void* const* d_in, const int* in_sizes, int n_in,
                              void* d_out, int out_size, void* d_ws, size_t ws_size,
                              hipStream_t stream)
{
    const float* z_src = (const float*)d_in[0];
    const float* z_dst = (const float*)d_in[1];
    const int*   eidx  = (const int*)d_in[2];
    const float* W1    = (const float*)d_in[3];
    const float* b1    = (const float*)d_in[4];
    const float* W2    = (const float*)d_in[5];
    const float* b2    = (const float*)d_in[6];
    float*       outp  = (float*)d_out;

    const int Nn = in_sizes[0] / HDIM;    // 100000
    const int E  = in_sizes[2] / 2;       // 2000000

    unsigned short* Abuf = (unsigned short*)d_ws;
    unsigned short* Bbuf = Abuf + (size_t)Nn * HDIM;
    unsigned short* Wt   = Bbuf + (size_t)Nn * HDIM;

    convert_w1<<<128, 256, 0, stream>>>(W1, Wt);

    const int tiles = (Nn + 63) >> 6;     // 1563
    node_gemm_v6<<<2 * tiles, 256, 0, stream>>>(
        z_src, z_dst, Wt, b1, Abuf, Bbuf, Nn, tiles);

    edge_decode_bf16<<<8192, 256, 0, stream>>>(Abuf, Bbuf, eidx, W2, b2, outp, E);
}